// Round 2
// baseline (2882.849 us; speedup 1.0000x reference)
//
#include <hip/hip_runtime.h>

// FixedActionDecoder: sims = (X/||X||row) @ (A/||A||col); segment-max over
// ACTION_INDEX=[0,0,0,0,1,1,1,1,1,2,3]; argmax; one-hot.
// Row-norm of X is argmax-invariant -> skipped entirely.
//
// Structure: one THREAD per row (no cross-lane reduction at all).
//  - A is normalized once into a __device__ f64 array by a prep kernel;
//    in the main loop its values are thread-uniform -> compiler emits s_load
//    + v_fma_f64 with SGPR-pair operands (A-side costs no VALU/vmem).
//  - X staged via per-wave LDS so global loads are full-128B-line fetches
//    (direct per-lane rows would be 64-way line splits + L1 thrash).
//  - Wave-private LDS buffer -> wave-synchronous, no __syncthreads needed
//    (grid-stride trip counts may diverge between waves of a block).
//  - f64 accumulation: one argmax flip = absmax 1.0 = fail; f32 rounding
//    (~1e-7..1e-6) vs typical segment-max gaps (~0.3) over 1e6 rows is a
//    coin flip. f64 VALU (~704 fma @ 4cyc / 64 rows) stays under HBM floor.

#define NP 11
#define WSTRIDE 16  // doubles per d-row of normalized A (128 B, aligned)

__device__ double g_W[64 * WSTRIDE];

__global__ void prep_anorm(const float* __restrict__ A) {
    int p = threadIdx.x;
    if (p < NP) {
        double ss = 0.0;
        #pragma unroll
        for (int d = 0; d < 64; ++d) {
            double v = (double)A[d * NP + p];
            ss += v * v;
        }
        double scale = 1.0 / fmax(sqrt(ss), 1e-8);
        #pragma unroll
        for (int d = 0; d < 64; ++d)
            g_W[d * WSTRIDE + p] = (double)A[d * NP + p] * scale;
    }
}

#define LROW 36  // LDS row stride in dwords: 32 data + 4 pad (16B-aligned,
                 // both ds_write and per-lane-row ds_read_b128 hit the
                 // 8-cycle/KB bank floor)

__global__ __launch_bounds__(256) void decode(const float* __restrict__ X,
                                              float* __restrict__ out, int B) {
    __shared__ float lds[4][64][LROW];  // 36864 B -> 4 blocks/CU, 16 waves/CU
    const int tid = threadIdx.x;
    const int lane = tid & 63;
    const int wv = tid >> 6;
    float(*buf)[LROW] = lds[wv];

    const int gwave = blockIdx.x * 4 + wv;
    const int nwaves = gridDim.x * 4;
    const float4* X4 = reinterpret_cast<const float4*>(X);

    for (int base = gwave * 64; base < B; base += nwaves * 64) {
        double s[NP];
        #pragma unroll
        for (int p = 0; p < NP; ++p) s[p] = 0.0;

        #pragma unroll
        for (int st = 0; st < 2; ++st) {  // d = st*32 .. st*32+31
            // Stage 64 rows x 32 floats. Instr i covers 8 full cache lines:
            // 8 rows, 8 lanes/row contiguous (128 B), rows at stride 256 B.
            #pragma unroll
            for (int i = 0; i < 8; ++i) {
                int fid = i * 64 + lane;  // 0..511
                int row = fid >> 3;       // 0..63
                int f = fid & 7;          // 0..7
                int r = base + row;
                if (r >= B) r = B - 1;  // tail clamp (harmless dup read)
                float4 v = X4[(size_t)r * 16 + st * 8 + f];
                *reinterpret_cast<float4*>(&buf[row][f * 4]) = v;
            }
            __builtin_amdgcn_wave_barrier();  // codegen ordering fence (no-op)

            // Each lane consumes its own row; W[] access is thread-uniform
            // -> s_load + v_fma_f64 with SGPR operand.
            #pragma unroll
            for (int k = 0; k < 8; ++k) {
                float4 xv = *reinterpret_cast<const float4*>(&buf[lane][k * 4]);
                int d = st * 32 + k * 4;
                double x0 = (double)xv.x, x1 = (double)xv.y;
                double x2 = (double)xv.z, x3 = (double)xv.w;
                #pragma unroll
                for (int p = 0; p < NP; ++p) {
                    double t = fma(x0, g_W[(d + 0) * WSTRIDE + p], s[p]);
                    t = fma(x1, g_W[(d + 1) * WSTRIDE + p], t);
                    t = fma(x2, g_W[(d + 2) * WSTRIDE + p], t);
                    s[p] = fma(x3, g_W[(d + 3) * WSTRIDE + p], t);
                }
            }
            __builtin_amdgcn_wave_barrier();
        }

        // Segment max per ACTION_INDEX = [0,0,0,0, 1,1,1,1,1, 2, 3]
        double m0 = fmax(fmax(s[0], s[1]), fmax(s[2], s[3]));
        double m1 = fmax(fmax(fmax(s[4], s[5]), s[6]), fmax(s[7], s[8]));
        double m2 = s[9], m3 = s[10];

        int idx = 0;
        double best = m0;
        if (m1 > best) { best = m1; idx = 1; }
        if (m2 > best) { best = m2; idx = 2; }
        if (m3 > best) { best = m3; idx = 3; }

        int r = base + lane;
        if (r < B) {
            float4 o;
            o.x = (idx == 0) ? 1.0f : 0.0f;
            o.y = (idx == 1) ? 1.0f : 0.0f;
            o.z = (idx == 2) ? 1.0f : 0.0f;
            o.w = (idx == 3) ? 1.0f : 0.0f;
            reinterpret_cast<float4*>(out)[r] = o;  // coalesced: lanes->rows
        }
    }
}

extern "C" void kernel_launch(void* const* d_in, const int* in_sizes, int n_in,
                              void* d_out, int out_size, void* d_ws, size_t ws_size,
                              hipStream_t stream) {
    const float* X = (const float*)d_in[0];
    const float* A = (const float*)d_in[1];
    float* out = (float*)d_out;
    const int B = in_sizes[0] / 64;

    hipLaunchKernelGGL(prep_anorm, dim3(1), dim3(64), 0, stream, A);
    hipLaunchKernelGGL(decode, dim3(2048), dim3(256), 0, stream, X, out, B);
}

// Round 4
// 88.644 us; speedup vs baseline: 32.5217x; 32.5217x over previous
//
#include <hip/hip_runtime.h>

// FixedActionDecoder: sims = (X/||x||) @ (A/||a||cols); segment-max over
// ACTION_INDEX=[0,0,0,0,1,1,1,1,1,2,3]; argmax; one-hot.
// Row-norm of X is argmax-invariant -> skipped.
//
//   prep       : normalize A in f64; store f32 W (chunked) + f64 W.
//   decode_f32 : memory-bound pass, one thread per TWO rows (128-row wave
//                tiles). X staged via per-wave LDS (full-128B-line coalesced
//                loads); W broadcast from LDS inside a #pragma unroll 1 loop
//                (round-2 lesson: unbounded hoisting of a uniform table blew
//                VGPRs to 256 and spilled 4 GB). Rows with top-2 action gap
//                < TAU flagged via __ballot, one u64 per 64 rows, no atomics.
//   repair     : recompute flagged rows (~1e3 of 1e6) in f64 — the numerics
//                that matched the reference exactly in rounds 1-2.
//
// Round-3 bug fixed here: ws-layout overlap (bits clobbered W64's tail).
// All side state now lives in __device__ globals -> no overlap, no ws_size
// assumption, fully rewritten every call (deterministic).

#define NP 11
#define TAU 1e-3f
#define LROW 36    // LDS row stride (dwords): 32 data + 4 pad (r2-verified 0-conflict)
#define NROWS 128  // rows per wave tile (2 rows per lane)

__device__ __align__(16) float g_W32[704];     // [(d>>2)*44 + (d&3)*11 + p]
__device__ double g_W64[704];                  // [d*11 + p]
__device__ unsigned long long g_bits[1 << 20]; // near-tie flags, 1 bit/row

__global__ void prep(const float* __restrict__ A) {
    int p = threadIdx.x;
    if (p < NP) {
        double ss = 0.0;
        for (int d = 0; d < 64; ++d) { double v = (double)A[d * NP + p]; ss += v * v; }
        double sc = 1.0 / fmax(sqrt(ss), 1e-8);
        for (int d = 0; d < 64; ++d) {
            double w = (double)A[d * NP + p] * sc;
            g_W64[d * NP + p] = w;
            g_W32[(d >> 2) * 44 + (d & 3) * NP + p] = (float)w;
        }
    }
}

__device__ __forceinline__ void argmax_gap(const float* s, int& idx, float& gap) {
    // Segment max per ACTION_INDEX = [0,0,0,0, 1,1,1,1,1, 2, 3]
    float m0 = fmaxf(fmaxf(s[0], s[1]), fmaxf(s[2], s[3]));
    float m1 = fmaxf(fmaxf(fmaxf(s[4], s[5]), s[6]), fmaxf(s[7], s[8]));
    float m2 = s[9], m3 = s[10];
    idx = 0; float best = m0;
    if (m1 > best) { best = m1; idx = 1; }
    if (m2 > best) { best = m2; idx = 2; }
    if (m3 > best) { best = m3; idx = 3; }
    float second = -3.4e38f;
    if (idx != 0) second = fmaxf(second, m0);
    if (idx != 1) second = fmaxf(second, m1);
    if (idx != 2) second = fmaxf(second, m2);
    if (idx != 3) second = fmaxf(second, m3);
    gap = best - second;
}

__global__ __launch_bounds__(128) void decode_f32(const float* __restrict__ X,
                                                  float* __restrict__ out, int B) {
    __shared__ float xbuf[2][NROWS][LROW];  // 36864 B, wave-private halves
    __shared__ float w_lds[704];            // 2816 B

    const int tid = threadIdx.x;
    const int lane = tid & 63;
    const int wv = tid >> 6;
    float(*buf)[LROW] = xbuf[wv];

    for (int t = tid; t < 176; t += 128)
        reinterpret_cast<float4*>(w_lds)[t] =
            reinterpret_cast<const float4*>(g_W32)[t];
    __syncthreads();

    const float4* X4 = reinterpret_cast<const float4*>(X);
    const int gwave = blockIdx.x * 2 + wv;
    const int nwaves = gridDim.x * 2;

    #pragma unroll 1
    for (int base = gwave * NROWS; base < B; base += nwaves * NROWS) {
        float acc0[NP], acc1[NP];
        #pragma unroll
        for (int p = 0; p < NP; ++p) { acc0[p] = 0.0f; acc1[p] = 0.0f; }

        #pragma unroll
        for (int st = 0; st < 2; ++st) {  // d half: st*32 .. st*32+31
            // Stage 128 rows x 32 floats; instr i covers 8 full 128B lines.
            #pragma unroll
            for (int i = 0; i < 16; ++i) {
                int fid = i * 64 + lane;  // 0..1023
                int row = fid >> 3;       // 0..127
                int f = fid & 7;          // 0..7
                int r = base + row;
                if (r >= B) r = B - 1;    // tail clamp (dup read, harmless)
                float4 v = X4[(size_t)r * 16 + st * 8 + f];
                *reinterpret_cast<float4*>(&buf[row][f * 4]) = v;
            }
            __builtin_amdgcn_wave_barrier();  // wave-private buf: fence only

            // Per 4-d chunk: 2 lane-varying b128 (X rows) + 11 uniform b128
            // (W broadcast) + 88 v_fma_f32. unroll 1 => W never bulk-hoisted.
            #pragma unroll 1
            for (int kk = 0; kk < 8; ++kk) {
                const float* wrow = &w_lds[(st * 8 + kk) * 44];
                float4 x0 = *reinterpret_cast<const float4*>(&buf[lane][kk * 4]);
                float4 x1 = *reinterpret_cast<const float4*>(&buf[lane + 64][kk * 4]);
                #pragma unroll
                for (int p = 0; p < NP; ++p) {
                    float w0 = wrow[0 * NP + p], w1 = wrow[1 * NP + p];
                    float w2 = wrow[2 * NP + p], w3 = wrow[3 * NP + p];
                    float t0 = fmaf(x0.x, w0, acc0[p]);
                    t0 = fmaf(x0.y, w1, t0);
                    t0 = fmaf(x0.z, w2, t0);
                    acc0[p] = fmaf(x0.w, w3, t0);
                    float t1 = fmaf(x1.x, w0, acc1[p]);
                    t1 = fmaf(x1.y, w1, t1);
                    t1 = fmaf(x1.z, w2, t1);
                    acc1[p] = fmaf(x1.w, w3, t1);
                }
            }
            __builtin_amdgcn_wave_barrier();
        }

        int idx0, idx1; float gap0, gap1;
        argmax_gap(acc0, idx0, gap0);
        argmax_gap(acc1, idx1, gap1);

        unsigned long long m0 = __ballot(gap0 < TAU);
        unsigned long long m1 = __ballot(gap1 < TAU);
        if (lane == 0) {
            g_bits[(base >> 6) + 0] = m0;
            g_bits[(base >> 6) + 1] = m1;
        }

        int r0 = base + lane, r1 = base + 64 + lane;
        if (r0 < B) {
            float4 o;
            o.x = (idx0 == 0) ? 1.0f : 0.0f;
            o.y = (idx0 == 1) ? 1.0f : 0.0f;
            o.z = (idx0 == 2) ? 1.0f : 0.0f;
            o.w = (idx0 == 3) ? 1.0f : 0.0f;
            reinterpret_cast<float4*>(out)[r0] = o;
        }
        if (r1 < B) {
            float4 o;
            o.x = (idx1 == 0) ? 1.0f : 0.0f;
            o.y = (idx1 == 1) ? 1.0f : 0.0f;
            o.z = (idx1 == 2) ? 1.0f : 0.0f;
            o.w = (idx1 == 3) ? 1.0f : 0.0f;
            reinterpret_cast<float4*>(out)[r1] = o;
        }
    }
}

__global__ __launch_bounds__(256) void repair(const float* __restrict__ X,
                                              float* __restrict__ out, int B) {
    const int nwords = (B + 63) >> 6;
    for (int t = blockIdx.x * blockDim.x + threadIdx.x; t < nwords;
         t += gridDim.x * blockDim.x) {
        unsigned long long m = g_bits[t];
        while (m) {
            int b = __builtin_ctzll(m);
            m &= m - 1;
            int row = t * 64 + b;
            if (row >= B) continue;

            double s[NP];
            #pragma unroll
            for (int p = 0; p < NP; ++p) s[p] = 0.0;
            #pragma unroll 1
            for (int d = 0; d < 64; ++d) {
                double x = (double)X[(size_t)row * 64 + d];
                #pragma unroll
                for (int p = 0; p < NP; ++p)
                    s[p] = fma(x, g_W64[d * NP + p], s[p]);
            }

            double m0 = fmax(fmax(s[0], s[1]), fmax(s[2], s[3]));
            double m1 = fmax(fmax(fmax(s[4], s[5]), s[6]), fmax(s[7], s[8]));
            double m2 = s[9], m3 = s[10];
            int idx = 0; double best = m0;
            if (m1 > best) { best = m1; idx = 1; }
            if (m2 > best) { best = m2; idx = 2; }
            if (m3 > best) { best = m3; idx = 3; }

            float4 o;
            o.x = (idx == 0) ? 1.0f : 0.0f;
            o.y = (idx == 1) ? 1.0f : 0.0f;
            o.z = (idx == 2) ? 1.0f : 0.0f;
            o.w = (idx == 3) ? 1.0f : 0.0f;
            reinterpret_cast<float4*>(out)[row] = o;
        }
    }
}

extern "C" void kernel_launch(void* const* d_in, const int* in_sizes, int n_in,
                              void* d_out, int out_size, void* d_ws, size_t ws_size,
                              hipStream_t stream) {
    const float* X = (const float*)d_in[0];
    const float* A = (const float*)d_in[1];
    float* out = (float*)d_out;
    const int B = in_sizes[0] / 64;

    hipLaunchKernelGGL(prep, dim3(1), dim3(64), 0, stream, A);
    hipLaunchKernelGGL(decode_f32, dim3(1024), dim3(128), 0, stream, X, out, B);
    hipLaunchKernelGGL(repair, dim3(128), dim3(256), 0, stream, X, out, B);
}